// Round 6
// baseline (82.433 us; speedup 1.0000x reference)
//
#include <hip/hip_runtime.h>

#define BB 8
#define SS 128
#define DD 480
#define EE 8
#define CC 10
#define KK 10
#define FF 994

// All tensors are fp32 (verified round 2/5: fp32 path passes, absmax 0.0156).

// Kernel 1: per-(b,s) row terms (fp32 workspace).
//   Arow[b,s,k] = gcn[b,s]·W[k,0:480]   + wp[b,s,s,:]·W[k,960:968]            (j-varying part)
//   Brow[b,s,k] = gcn[b,s]·W[k,480:960] + wp[b,s,s,:]·W[k,968:976] + bias[k]  (i-varying part)
__global__ __launch_bounds__(256) void rows_kernel(
    const float* __restrict__ gcn,    // [B,S,D]
    const float* __restrict__ wp,     // [B,S,S,E]
    const float* __restrict__ W,      // [K,F]
    const float* __restrict__ bias,   // [K]
    float* __restrict__ Arow,         // [B*S,K]
    float* __restrict__ Brow)         // [B*S,K]
{
    __shared__ float g[DD];
    const int row = blockIdx.x;            // b*S + s
    const int s   = row & (SS - 1);

    // stage gcn row: 480 fp32 = 120 float4 (row base = 1920 B * row, 16B-aligned)
    const float4* g4 = reinterpret_cast<const float4*>(gcn + (size_t)row * DD);
    for (int t = threadIdx.x; t < DD / 4; t += 256) {
        const float4 v = g4[t];
        g[4 * t + 0] = v.x; g[4 * t + 1] = v.y;
        g[4 * t + 2] = v.z; g[4 * t + 3] = v.w;
    }
    __syncthreads();

    const int wave = threadIdx.x >> 6;     // 0..3
    const int lane = threadIdx.x & 63;

    // 20 dot products, 5 per wave, fully unrolled for load ILP.
    #pragma unroll
    for (int q = 0; q < 5; ++q) {
        const int t   = wave * 5 + q;      // 0..19: t<10 -> Arow[k=t], else Brow[k=t-10]
        const int k   = (t < KK) ? t : t - KK;
        const int off = (t < KK) ? 0 : DD;
        // W row slice base index k*994+off is even -> 8B-aligned -> float2 safe
        const float2* w2 = reinterpret_cast<const float2*>(W + (size_t)k * FF + off);

        float acc = 0.f;
        #pragma unroll
        for (int r = 0; r < 4; ++r) {
            const int idx = lane + 64 * r;             // need < 240
            if (idx < DD / 2) {
                const float2 u = w2[idx];
                acc += g[2 * idx] * u.x + g[2 * idx + 1] * u.y;
            }
        }
        #pragma unroll
        for (int o = 32; o > 0; o >>= 1)
            acc += __shfl_down(acc, o, 64);

        if (lane == 0) {
            // diag edge term: wp[b,s,s,:] · W[k, 960 or 968 : +8]
            const float* wpd = wp + ((size_t)row * SS + s) * EE;
            const float* we  = W + (size_t)k * FF + ((t < KK) ? 2 * DD : 2 * DD + EE);
            float e = 0.f;
            #pragma unroll
            for (int ee = 0; ee < EE; ++ee)
                e += wpd[ee] * we[ee];
            const float r = acc + e;
            if (t < KK) Arow[row * KK + k] = r;
            else        Brow[row * KK + k] = r + bias[k];
        }
    }
}

// Kernel 2: 512 threads = 4 i-rows of 128 pixels.
// out[b,i,j,k] = Arow[b,j,k] + Brow[b,i,k] + wp[b,i,j,:]·W[k,976:984]
//   + label[..,0]*W[k,984] + (j>=i)*sum_{c=1..3} label[..c]*W[k,984+c]
//   + (j<=i)*sum_{c=4..9} label[..c]*W[k,984+c]
__global__ __launch_bounds__(512) void pixel_kernel(
    const float* __restrict__ label,  // [B,S,S,C]
    const float* __restrict__ wp,     // [B,S,S,E]
    const float* __restrict__ W,      // [K,F]
    const float* __restrict__ Arow,   // [B*S,K]
    const float* __restrict__ Brow,   // [B*S,K]
    float* __restrict__ out)          // [B,S,S,K]
{
    const int b  = blockIdx.x >> 5;           // 8 b's x 32 blocks
    const int i0 = (blockIdx.x & 31) * 4;     // 4 i-rows per block

    __shared__ float w5[KK][EE];              // W[:,976:984]
    __shared__ float w6[KK][CC];              // W[:,984:994]
    __shared__ float brow[4][KK];
    __shared__ float arow[SS][KK + 1];        // +1 pad: stride 11 -> <=2-way banks (free)

    {
        const int t = threadIdx.x;
        if (t < 80) {
            w5[t >> 3][t & 7] = W[(t >> 3) * FF + 2 * DD + 2 * EE + (t & 7)];       // col 976+
        } else if (t < 180) {
            const int tt = t - 80;
            w6[tt / 10][tt % 10] = W[(tt / 10) * FF + 2 * DD + 3 * EE + (tt % 10)]; // col 984+
        } else if (t < 220) {
            const int tt = t - 180;
            brow[tt / 10][tt % 10] = Brow[(b * SS + i0 + tt / 10) * KK + (tt % 10)];
        }
    }
    for (int u = threadIdx.x; u < SS * KK; u += 512)
        arow[u / KK][u % KK] = Arow[(size_t)b * SS * KK + u];
    __syncthreads();

    const int half = threadIdx.x >> 7;        // 0..3 -> which i-row
    const int i    = i0 + half;
    const int j    = threadIdx.x & 127;
    const size_t pix = ((size_t)(b * SS + i)) * SS + j;

    // wp pixel: 8 fp32 = 32 B, 32B-aligned -> 2x float4
    float wpe[EE];
    {
        const float4* p4 = reinterpret_cast<const float4*>(wp + pix * EE);
        const float4 a = p4[0], c = p4[1];
        wpe[0] = a.x; wpe[1] = a.y; wpe[2] = a.z; wpe[3] = a.w;
        wpe[4] = c.x; wpe[5] = c.y; wpe[6] = c.z; wpe[7] = c.w;
    }
    // label pixel: 10 fp32 = 40 B, 8B-aligned -> 5x float2
    float lc[CC];
    {
        const float2* p2 = reinterpret_cast<const float2*>(label + pix * CC);
        #pragma unroll
        for (int p = 0; p < 5; ++p) {
            const float2 v = p2[p];
            lc[2 * p] = v.x; lc[2 * p + 1] = v.y;
        }
    }

    const float mu = (j >= i) ? 1.f : 0.f;    // upper-tri, channels 1..3
    const float ml = (j <= i) ? 1.f : 0.f;    // lower-tri, channels 4..9
    #pragma unroll
    for (int c = 1; c < 4; ++c) lc[c] *= mu;
    #pragma unroll
    for (int c = 4; c < CC; ++c) lc[c] *= ml;

    float o[KK];
    #pragma unroll
    for (int k = 0; k < KK; ++k) {
        float acc = arow[j][k] + brow[half][k];
        #pragma unroll
        for (int e = 0; e < EE; ++e) acc += wpe[e] * w5[k][e];
        #pragma unroll
        for (int c = 0; c < CC; ++c) acc += lc[c] * w6[k][c];
        o[k] = acc;
    }

    float2* op = reinterpret_cast<float2*>(out + pix * KK);
    #pragma unroll
    for (int p = 0; p < 5; ++p)
        op[p] = make_float2(o[2 * p], o[2 * p + 1]);
}

extern "C" void kernel_launch(void* const* d_in, const int* in_sizes, int n_in,
                              void* d_out, int out_size, void* d_ws, size_t ws_size,
                              hipStream_t stream) {
    const float* gcn   = (const float*)d_in[0];  // [8,128,480]
    const float* label = (const float*)d_in[1];  // [8,128,128,10]
    const float* wp    = (const float*)d_in[2];  // [8,128,128,8]
    // d_in[3] = tensor_masks (all ones, unused by the math)
    const float* W     = (const float*)d_in[4];  // [10,994]
    const float* bias  = (const float*)d_in[5];  // [10]
    float* out = (float*)d_out;                  // [8,128,128,10]

    float* Arow = (float*)d_ws;                  // [1024,10] fp32
    float* Brow = Arow + BB * SS * KK;           // [1024,10] fp32

    rows_kernel<<<BB * SS, 256, 0, stream>>>(gcn, wp, W, bias, Arow, Brow);
    pixel_kernel<<<BB * SS / 4, 512, 0, stream>>>(label, wp, W, Arow, Brow, out);
}